// Round 8
// baseline (36.263 us; speedup 1.0000x reference)
//
#include <hip/hip_runtime.h>

// Problem constants: DIM=4096, WIDTH=4, POOL=512, BATCH=256, SEQ=16
constexpr int DIM   = 4096;
constexpr int WIDTH = 4;
constexpr int POOL  = 512;
constexpr int BATCH = 256;
constexpr int SEQ   = 16;

// float2 per conv thread: 2048 columns per batch row -> 8 blocks of 256.
constexpr int BLK_PER_B   = (DIM / 2) / 256;      // 8
constexpr int CONV_BLOCKS = BLK_PER_B * BATCH;    // 2048 == total grid

typedef float f32x2 __attribute__((ext_vector_type(2)));
typedef float f32x4 __attribute__((ext_vector_type(4)));

__device__ __forceinline__ f32x2 ld2(const float* p) {
    return *reinterpret_cast<const f32x2*>(p);
}
__device__ __forceinline__ void st2(float* p, f32x2 v) {
    *reinterpret_cast<f32x2*>(p) = v;
}
__device__ __forceinline__ f32x4 ld4(const float* p) {
    return *reinterpret_cast<const f32x4*>(p);
}
__device__ __forceinline__ void st4(float* p, f32x4 v) {
    *reinterpret_cast<f32x4*>(p) = v;
}
// Fast SiLU: v * rcp(1 + exp(-v)); ~1ulp, invisible at bf16-grade threshold.
__device__ __forceinline__ float fast_silu(float v) {
    return v * __builtin_amdgcn_rcpf(1.0f + __expf(-v));
}

// ---------------------------------------------------------------------------
// 2048 blocks x 256 threads, no LDS, no barriers, no duplicate reads.
//   Conv: thread owns one float2 column of one batch row. Preload all 19 rows
//     (3 state + 16 x, 8 B each) + weights + bias (~48 payload VGPRs), then
//     16x conv+SiLU+store. x rows 13..15 (already in regs) -> fused state
//     scatter to out_state[idx[b]].
//   Copy: block also owns one QUARTER of state row (blk>>2). Membership test
//     first (wave ballot over int4-loaded idxs, uniform, no LDS/barrier);
//     loads only if the row is NOT conv-owned (keeps FETCH at R5 level),
//     issued before conv compute so their latency hides under it.
//   Write sets are disjoint => no inter-block ordering needed.
// ---------------------------------------------------------------------------
__global__ __launch_bounds__(256, 8) void fused_conv_update_kernel(
    const float* __restrict__ x,           // [BATCH, SEQ, DIM]
    const float* __restrict__ conv_state,  // [POOL, WIDTH-1, DIM]
    const float* __restrict__ weight,      // [WIDTH, DIM]
    const float* __restrict__ bias,        // [DIM]
    const int*   __restrict__ idxs,        // [BATCH]
    float*       __restrict__ out,         // [BATCH, SEQ, DIM]
    float*       __restrict__ out_state)   // [POOL, WIDTH-1, DIM]
{
    const int blk  = blockIdx.x;
    const int b    = blk >> 3;                       // blk / BLK_PER_B
    const int part = blk & (BLK_PER_B - 1);
    const int d    = (part * 256 + threadIdx.x) * 2; // float2 column
    const int idx  = idxs[b];

    const float* xb = x + (size_t)b * SEQ * DIM + d;
    const float* st = conv_state + (size_t)idx * (WIDTH - 1) * DIM + d;

    // ---- Conv loads: 19 rows, all independent, issued up front ----
    f32x2 xv[SEQ + WIDTH - 1];
    xv[0] = ld2(st + 0 * DIM);
    xv[1] = ld2(st + 1 * DIM);
    xv[2] = ld2(st + 2 * DIM);
#pragma unroll
    for (int s = 0; s < SEQ; ++s)
        xv[WIDTH - 1 + s] = ld2(xb + (size_t)s * DIM);

    const f32x2 w0 = ld2(weight + 0 * DIM + d);
    const f32x2 w1 = ld2(weight + 1 * DIM + d);
    const f32x2 w2 = ld2(weight + 2 * DIM + d);
    const f32x2 w3 = ld2(weight + 3 * DIM + d);
    const f32x2 bs = ld2(bias + d);

    // ---- Copy part: membership test, then conditional early loads ----
    const int row = blk >> 2;                 // 2048 blocks -> 512 rows x 4
    const int q   = blk & 3;
    const int4 iv = *reinterpret_cast<const int4*>(idxs + (threadIdx.x & 63) * 4);
    const bool hit = (iv.x == row) | (iv.y == row) | (iv.z == row) | (iv.w == row);
    const bool skip = (__ballot(hit) != 0ull);

    constexpr int Q_FLOATS = (WIDTH - 1) * DIM / 4;   // 3072 floats per quarter
    const float* csrc = conv_state + (size_t)row * (WIDTH - 1) * DIM
                      + (size_t)q * Q_FLOATS + threadIdx.x * 4;
    f32x4 c0, c1, c2;
    if (!skip) {
        c0 = ld4(csrc + 0 * 1024);
        c1 = ld4(csrc + 1 * 1024);
        c2 = ld4(csrc + 2 * 1024);
    }

    // ---- Conv compute + stores ----
    float* ob = out + (size_t)b * SEQ * DIM + d;
#pragma unroll
    for (int s = 0; s < SEQ; ++s) {
        f32x2 acc = bs + xv[s] * w0 + xv[s + 1] * w1 + xv[s + 2] * w2 + xv[s + 3] * w3;
        acc.x = fast_silu(acc.x);
        acc.y = fast_silu(acc.y);
        st2(ob + (size_t)s * DIM, acc);
    }

    // State scatter: xv[16..18] = x rows 13,14,15.
    float* sd = out_state + (size_t)idx * (WIDTH - 1) * DIM + d;
    st2(sd + 0 * DIM, xv[SEQ + 0]);
    st2(sd + 1 * DIM, xv[SEQ + 1]);
    st2(sd + 2 * DIM, xv[SEQ + 2]);

    // ---- Copy stores ----
    if (!skip) {
        float* cdst = out_state + (size_t)row * (WIDTH - 1) * DIM
                    + (size_t)q * Q_FLOATS + threadIdx.x * 4;
        st4(cdst + 0 * 1024, c0);
        st4(cdst + 1 * 1024, c1);
        st4(cdst + 2 * 1024, c2);
    }
}

// ---------------------------------------------------------------------------
extern "C" void kernel_launch(void* const* d_in, const int* in_sizes, int n_in,
                              void* d_out, int out_size, void* d_ws, size_t ws_size,
                              hipStream_t stream)
{
    const float* x          = (const float*)d_in[0];
    const float* conv_state = (const float*)d_in[1];
    const float* weight     = (const float*)d_in[2];
    const float* bias       = (const float*)d_in[3];
    const int*   idxs       = (const int*)  d_in[4];

    float* out       = (float*)d_out;                    // [BATCH,SEQ,DIM]
    float* out_state = out + (size_t)BATCH * SEQ * DIM;  // [POOL,WIDTH-1,DIM]

    fused_conv_update_kernel<<<CONV_BLOCKS, 256, 0, stream>>>(
        x, conv_state, weight, bias, idxs, out, out_state);
}

// Round 9
// 32.993 us; speedup vs baseline: 1.0991x; 1.0991x over previous
//
#include <hip/hip_runtime.h>

// Problem constants: DIM=4096, WIDTH=4, POOL=512, BATCH=256, SEQ=16
constexpr int DIM   = 4096;
constexpr int WIDTH = 4;
constexpr int POOL  = 512;
constexpr int BATCH = 256;
constexpr int SEQ   = 16;

// One wave (64 threads) per block.
//   Conv blocks: 16 wave-columns per batch row (16 * 64 lanes * 4 floats = 4096).
//   Copy blocks: 8 per state row (each moves 1/8 of 12288 floats = 6 f4/lane).
constexpr int WAVES_PER_B  = DIM / (4 * 64);          // 16
constexpr int CONV_BLOCKS  = WAVES_PER_B * BATCH;     // 4096
constexpr int COPY_PER_ROW = 8;
constexpr int COPY_BLOCKS  = COPY_PER_ROW * POOL;     // 4096
constexpr int TOTAL_BLOCKS = CONV_BLOCKS + COPY_BLOCKS;

typedef float f32x4 __attribute__((ext_vector_type(4)));

__device__ __forceinline__ f32x4 ld4(const float* p) {
    return *reinterpret_cast<const f32x4*>(p);
}
__device__ __forceinline__ void st4(float* p, f32x4 v) {
    *reinterpret_cast<f32x4*>(p) = v;
}
// Fast SiLU: v * rcp(1 + exp(-v)); ~1ulp, invisible at bf16-grade threshold.
__device__ __forceinline__ float fast_silu(float v) {
    return v * __builtin_amdgcn_rcpf(1.0f + __expf(-v));
}

// ---------------------------------------------------------------------------
// 8192 single-wave blocks, no LDS, no barriers, minimal traffic (184.6 MB).
//   Conv wave: preload 19 rows (3 state + 16 x) + weights + bias, 16x
//     conv+SiLU+store; x rows 13..15 (already in regs) -> fused state scatter.
//   Copy wave: 1/8 of state row; ballot membership test (64 lanes x int4 =
//     all 256 indices) BEFORE the loads -> indexed rows cost zero fetch.
//   Write sets are disjoint => no inter-block ordering needed.
// ---------------------------------------------------------------------------
__global__ __launch_bounds__(64) void fused_conv_update_kernel(
    const float* __restrict__ x,           // [BATCH, SEQ, DIM]
    const float* __restrict__ conv_state,  // [POOL, WIDTH-1, DIM]
    const float* __restrict__ weight,      // [WIDTH, DIM]
    const float* __restrict__ bias,        // [DIM]
    const int*   __restrict__ idxs,        // [BATCH]
    float*       __restrict__ out,         // [BATCH, SEQ, DIM]
    float*       __restrict__ out_state)   // [POOL, WIDTH-1, DIM]
{
    const int blk  = blockIdx.x;
    const int lane = threadIdx.x;          // 0..63

    if (blk < CONV_BLOCKS) {
        // ------------- conv + SiLU + fused state scatter -------------
        const int b   = blk >> 4;                       // blk / WAVES_PER_B
        const int wc  = blk & (WAVES_PER_B - 1);
        const int d   = (wc * 64 + lane) * 4;
        const int idx = idxs[b];                        // wave-uniform s_load

        const float* xb = x + (size_t)b * SEQ * DIM + d;
        const float* st = conv_state + (size_t)idx * (WIDTH - 1) * DIM + d;

        // Preload all 19 rows (independent 1 KB wave-loads).
        f32x4 xv[SEQ + WIDTH - 1];
        xv[0] = ld4(st + 0 * DIM);
        xv[1] = ld4(st + 1 * DIM);
        xv[2] = ld4(st + 2 * DIM);
#pragma unroll
        for (int s = 0; s < SEQ; ++s)
            xv[WIDTH - 1 + s] = ld4(xb + (size_t)s * DIM);

        const f32x4 w0 = ld4(weight + 0 * DIM + d);
        const f32x4 w1 = ld4(weight + 1 * DIM + d);
        const f32x4 w2 = ld4(weight + 2 * DIM + d);
        const f32x4 w3 = ld4(weight + 3 * DIM + d);
        const f32x4 bs = ld4(bias + d);

        float* ob = out + (size_t)b * SEQ * DIM + d;
#pragma unroll
        for (int s = 0; s < SEQ; ++s) {
            f32x4 acc = bs + xv[s] * w0 + xv[s + 1] * w1 + xv[s + 2] * w2 + xv[s + 3] * w3;
            acc.x = fast_silu(acc.x);
            acc.y = fast_silu(acc.y);
            acc.z = fast_silu(acc.z);
            acc.w = fast_silu(acc.w);
            st4(ob + (size_t)s * DIM, acc);
        }

        // New state = x rows 13..15 = xv[16..18].
        float* sd = out_state + (size_t)idx * (WIDTH - 1) * DIM + d;
        st4(sd + 0 * DIM, xv[SEQ + 0]);
        st4(sd + 1 * DIM, xv[SEQ + 1]);
        st4(sd + 2 * DIM, xv[SEQ + 2]);
    } else {
        // ------------- selective 1/8-row state copy -------------
        const int cblk = blk - CONV_BLOCKS;
        const int row  = cblk >> 3;                     // 0..511
        const int e    = cblk & (COPY_PER_ROW - 1);     // eighth

        // Ballot membership test: 64 lanes x int4 = all 256 indices.
        const int4 iv = *reinterpret_cast<const int4*>(idxs + lane * 4);
        const bool hit = (iv.x == row) | (iv.y == row) | (iv.z == row) | (iv.w == row);
        if (__ballot(hit) != 0ull) return;              // conv path owns this row

        constexpr int E_FLOATS = (WIDTH - 1) * DIM / COPY_PER_ROW;  // 1536
        const float* src = conv_state + (size_t)row * (WIDTH - 1) * DIM
                         + (size_t)e * E_FLOATS + lane * 4;
        float* dst = out_state + (size_t)row * (WIDTH - 1) * DIM
                   + (size_t)e * E_FLOATS + lane * 4;

        // 6 x (ld4 + st4), stride 64 lanes * 4 floats = 256 floats.
        f32x4 c0 = ld4(src + 0 * 256);
        f32x4 c1 = ld4(src + 1 * 256);
        f32x4 c2 = ld4(src + 2 * 256);
        f32x4 c3 = ld4(src + 3 * 256);
        f32x4 c4 = ld4(src + 4 * 256);
        f32x4 c5 = ld4(src + 5 * 256);
        st4(dst + 0 * 256, c0);
        st4(dst + 1 * 256, c1);
        st4(dst + 2 * 256, c2);
        st4(dst + 3 * 256, c3);
        st4(dst + 4 * 256, c4);
        st4(dst + 5 * 256, c5);
    }
}

// ---------------------------------------------------------------------------
extern "C" void kernel_launch(void* const* d_in, const int* in_sizes, int n_in,
                              void* d_out, int out_size, void* d_ws, size_t ws_size,
                              hipStream_t stream)
{
    const float* x          = (const float*)d_in[0];
    const float* conv_state = (const float*)d_in[1];
    const float* weight     = (const float*)d_in[2];
    const float* bias       = (const float*)d_in[3];
    const int*   idxs       = (const int*)  d_in[4];

    float* out       = (float*)d_out;                    // [BATCH,SEQ,DIM]
    float* out_state = out + (size_t)BATCH * SEQ * DIM;  // [POOL,WIDTH-1,DIM]

    fused_conv_update_kernel<<<TOTAL_BLOCKS, 64, 0, stream>>>(
        x, conv_state, weight, bias, idxs, out, out_state);
}

// Round 10
// 32.732 us; speedup vs baseline: 1.1079x; 1.0080x over previous
//
#include <hip/hip_runtime.h>

// Problem constants: DIM=4096, WIDTH=4, POOL=512, BATCH=256, SEQ=16
constexpr int DIM   = 4096;
constexpr int WIDTH = 4;
constexpr int POOL  = 512;
constexpr int BATCH = 256;
constexpr int SEQ   = 16;

// One wave (64 threads) per block.
constexpr int WAVES_PER_B  = DIM / (4 * 64);          // 16
constexpr int CONV_BLOCKS  = WAVES_PER_B * BATCH;     // 4096
constexpr int COPY_PER_ROW = 8;
constexpr int COPY_BLOCKS  = COPY_PER_ROW * POOL;     // 4096
constexpr int TOTAL_BLOCKS = CONV_BLOCKS + COPY_BLOCKS;

typedef float f32x4 __attribute__((ext_vector_type(4)));

__device__ __forceinline__ f32x4 ld4(const float* p) {
    return *reinterpret_cast<const f32x4*>(p);
}
// Non-temporal store: outputs are write-only streams, never re-read by this
// kernel. NT avoids L2/L3 write-allocate, so the 92 MB input set (x +
// conv_state) stays L3-resident across graph replays. (R3's NT regression was
// from NT LOADS, which killed the L3 read hits; stores were never isolated.)
__device__ __forceinline__ void st4_nt(float* p, f32x4 v) {
    __builtin_nontemporal_store(v, reinterpret_cast<f32x4*>(p));
}
// Fast SiLU: v * rcp(1 + exp(-v)); ~1ulp, invisible at bf16-grade threshold.
__device__ __forceinline__ float fast_silu(float v) {
    return v * __builtin_amdgcn_rcpf(1.0f + __expf(-v));
}

// ---------------------------------------------------------------------------
// 8192 single-wave blocks, no LDS, no barriers, minimal traffic (184.6 MB
// logical). Cached loads + non-temporal stores.
//   Conv wave: preload 19 rows (3 state + 16 x) + weights + bias, 16x
//     conv+SiLU+store; x rows 13..15 (already in regs) -> fused state scatter.
//   Copy wave: 1/8 of state row; ballot membership test (64 lanes x int4 =
//     all 256 indices) BEFORE the loads -> indexed rows cost zero fetch.
//   Write sets are disjoint => no inter-block ordering needed.
// ---------------------------------------------------------------------------
__global__ __launch_bounds__(64) void fused_conv_update_kernel(
    const float* __restrict__ x,           // [BATCH, SEQ, DIM]
    const float* __restrict__ conv_state,  // [POOL, WIDTH-1, DIM]
    const float* __restrict__ weight,      // [WIDTH, DIM]
    const float* __restrict__ bias,        // [DIM]
    const int*   __restrict__ idxs,        // [BATCH]
    float*       __restrict__ out,         // [BATCH, SEQ, DIM]
    float*       __restrict__ out_state)   // [POOL, WIDTH-1, DIM]
{
    const int blk  = blockIdx.x;
    const int lane = threadIdx.x;          // 0..63

    if (blk < CONV_BLOCKS) {
        // ------------- conv + SiLU + fused state scatter -------------
        const int b   = blk >> 4;                       // blk / WAVES_PER_B
        const int wc  = blk & (WAVES_PER_B - 1);
        const int d   = (wc * 64 + lane) * 4;
        const int idx = idxs[b];                        // wave-uniform s_load

        const float* xb = x + (size_t)b * SEQ * DIM + d;
        const float* st = conv_state + (size_t)idx * (WIDTH - 1) * DIM + d;

        // Preload all 19 rows (independent 1 KB wave-loads).
        f32x4 xv[SEQ + WIDTH - 1];
        xv[0] = ld4(st + 0 * DIM);
        xv[1] = ld4(st + 1 * DIM);
        xv[2] = ld4(st + 2 * DIM);
#pragma unroll
        for (int s = 0; s < SEQ; ++s)
            xv[WIDTH - 1 + s] = ld4(xb + (size_t)s * DIM);

        const f32x4 w0 = ld4(weight + 0 * DIM + d);
        const f32x4 w1 = ld4(weight + 1 * DIM + d);
        const f32x4 w2 = ld4(weight + 2 * DIM + d);
        const f32x4 w3 = ld4(weight + 3 * DIM + d);
        const f32x4 bs = ld4(bias + d);

        float* ob = out + (size_t)b * SEQ * DIM + d;
#pragma unroll
        for (int s = 0; s < SEQ; ++s) {
            f32x4 acc = bs + xv[s] * w0 + xv[s + 1] * w1 + xv[s + 2] * w2 + xv[s + 3] * w3;
            acc.x = fast_silu(acc.x);
            acc.y = fast_silu(acc.y);
            acc.z = fast_silu(acc.z);
            acc.w = fast_silu(acc.w);
            st4_nt(ob + (size_t)s * DIM, acc);
        }

        // New state = x rows 13..15 = xv[16..18].
        float* sd = out_state + (size_t)idx * (WIDTH - 1) * DIM + d;
        st4_nt(sd + 0 * DIM, xv[SEQ + 0]);
        st4_nt(sd + 1 * DIM, xv[SEQ + 1]);
        st4_nt(sd + 2 * DIM, xv[SEQ + 2]);
    } else {
        // ------------- selective 1/8-row state copy -------------
        const int cblk = blk - CONV_BLOCKS;
        const int row  = cblk >> 3;                     // 0..511
        const int e    = cblk & (COPY_PER_ROW - 1);     // eighth

        // Ballot membership test: 64 lanes x int4 = all 256 indices.
        const int4 iv = *reinterpret_cast<const int4*>(idxs + lane * 4);
        const bool hit = (iv.x == row) | (iv.y == row) | (iv.z == row) | (iv.w == row);
        if (__ballot(hit) != 0ull) return;              // conv path owns this row

        constexpr int E_FLOATS = (WIDTH - 1) * DIM / COPY_PER_ROW;  // 1536
        const float* src = conv_state + (size_t)row * (WIDTH - 1) * DIM
                         + (size_t)e * E_FLOATS + lane * 4;
        float* dst = out_state + (size_t)row * (WIDTH - 1) * DIM
                   + (size_t)e * E_FLOATS + lane * 4;

        // 6 x (ld4 + st4_nt), stride 64 lanes * 4 floats = 256 floats.
        f32x4 c0 = ld4(src + 0 * 256);
        f32x4 c1 = ld4(src + 1 * 256);
        f32x4 c2 = ld4(src + 2 * 256);
        f32x4 c3 = ld4(src + 3 * 256);
        f32x4 c4 = ld4(src + 4 * 256);
        f32x4 c5 = ld4(src + 5 * 256);
        st4_nt(dst + 0 * 256, c0);
        st4_nt(dst + 1 * 256, c1);
        st4_nt(dst + 2 * 256, c2);
        st4_nt(dst + 3 * 256, c3);
        st4_nt(dst + 4 * 256, c4);
        st4_nt(dst + 5 * 256, c5);
    }
}

// ---------------------------------------------------------------------------
extern "C" void kernel_launch(void* const* d_in, const int* in_sizes, int n_in,
                              void* d_out, int out_size, void* d_ws, size_t ws_size,
                              hipStream_t stream)
{
    const float* x          = (const float*)d_in[0];
    const float* conv_state = (const float*)d_in[1];
    const float* weight     = (const float*)d_in[2];
    const float* bias       = (const float*)d_in[3];
    const int*   idxs       = (const int*)  d_in[4];

    float* out       = (float*)d_out;                    // [BATCH,SEQ,DIM]
    float* out_state = out + (size_t)BATCH * SEQ * DIM;  // [POOL,WIDTH-1,DIM]

    fused_conv_update_kernel<<<TOTAL_BLOCKS, 64, 0, stream>>>(
        x, conv_state, weight, bias, idxs, out, out_state);
}